// Round 1
// baseline (439.927 us; speedup 1.0000x reference)
//
#include <hip/hip_runtime.h>
#include <math.h>

#define NIMG 4
#define NCLS 15
#define HDIM 256
#define WDIM 256
#define HW (HDIM*WDIM)
#define NANG 90
#define KTOP 400
#define POSTN 100
#define NBINS 4096
#define CAP 4096
#define SUPW 13   // uint32 words per suppress-row (400 bits)

// ---- workspace layout (bytes) ----
#define HIST_OFF   0
#define CNT_OFF    (NIMG*NBINS*4)              // 65536
#define TBIN_OFF   (CNT_OFF + 64)              // 65600
#define SUP_OFF    (TBIN_OFF + 64)             // 65664
#define SUP_BYTES  (NIMG*KTOP*SUPW*4)          // 83200
#define ZERO_BYTES (SUP_OFF + SUP_BYTES)       // 148864  (memset region)
#define CAND_OFF   ZERO_BYTES                  // 8-aligned
#define COR_OFF    (CAND_OFF + NIMG*CAP*8)
#define AREA_OFF   (COR_OFF + NIMG*KTOP*8*4)
#define LAB_OFF    (AREA_OFF + NIMG*KTOP*4)
#define SC_OFF     (LAB_OFF + NIMG*KTOP*4)
#define VAL_OFF    (SC_OFF + NIMG*KTOP*4)

__device__ __forceinline__ float sigmoidf(float x) {
    return 1.0f / (1.0f + expf(-x));
}

// ---------------- K1: histogram of comb scores ----------------
__global__ void k_hist(const float* __restrict__ cls, const float* __restrict__ ctr,
                       int* __restrict__ hist) {
    __shared__ int sh[NBINS];
    const int n = blockIdx.y;
    const int p = blockIdx.x * 256 + threadIdx.x;
    for (int b = threadIdx.x; b < NBINS; b += 256) sh[b] = 0;
    __syncthreads();
    float cv = sigmoidf(ctr[n * HW + p]);
    for (int j = 0; j < NCLS; ++j) {
        float s = sigmoidf(cls[(n * NCLS + j) * HW + p]);
        if (s > 0.05f) {
            float comb = s * cv;
            int b = (int)(comb * 4096.0f);
            b = b < 0 ? 0 : (b > NBINS - 1 ? NBINS - 1 : b);
            atomicAdd(&sh[b], 1);
        }
    }
    __syncthreads();
    for (int b = threadIdx.x; b < NBINS; b += 256) {
        int v = sh[b];
        if (v) atomicAdd(&hist[n * NBINS + b], v);
    }
}

// ---------------- K2: find threshold bin (>= 400 above) ----------------
__global__ void k_thresh(const int* __restrict__ hist, int* __restrict__ tbin) {
    const int n = blockIdx.x;
    __shared__ int sh[NBINS];
    __shared__ int part[256];
    for (int b = threadIdx.x; b < NBINS; b += 256) sh[b] = hist[n * NBINS + b];
    __syncthreads();
    int s = 0;
    int base = threadIdx.x * 16;
    for (int b = 0; b < 16; ++b) s += sh[base + b];
    part[threadIdx.x] = s;
    __syncthreads();
    if (threadIdx.x == 0) {
        int acc = 0, seg = -1, above = 0;
        for (int sg = 255; sg >= 0; --sg) {
            int ps = part[sg];
            if (acc + ps >= KTOP) { seg = sg; above = acc; break; }
            acc += ps;
        }
        int t = 0;
        if (seg >= 0) {
            int a2 = above;
            t = seg * 16;
            for (int b = seg * 16 + 15; b >= seg * 16; --b) {
                a2 += sh[b];
                if (a2 >= KTOP) { t = b; break; }
            }
        }
        tbin[n] = t;
    }
}

// ---------------- K3: collect candidates with bin >= t ----------------
__global__ void k_collect(const float* __restrict__ cls, const float* __restrict__ ctr,
                          const int* __restrict__ tbin, int* __restrict__ cnt,
                          unsigned long long* __restrict__ cand) {
    const int n = blockIdx.y;
    const int p = blockIdx.x * 256 + threadIdx.x;
    const int t = tbin[n];
    float cv = sigmoidf(ctr[n * HW + p]);
    for (int j = 0; j < NCLS; ++j) {
        float s = sigmoidf(cls[(n * NCLS + j) * HW + p]);
        if (s > 0.05f) {
            float comb = s * cv;
            int b = (int)(comb * 4096.0f);
            b = b < 0 ? 0 : (b > NBINS - 1 ? NBINS - 1 : b);
            if (b >= t) {
                int pos = atomicAdd(&cnt[n], 1);
                if (pos < CAP) {
                    unsigned int fb = __float_as_uint(comb);
                    unsigned int idx = (unsigned int)(p * NCLS + j);
                    cand[n * CAP + pos] =
                        ((unsigned long long)fb << 32) | (unsigned long long)(~idx);
                }
            }
        }
    }
}

// ---------------- K4a: sort + gather + decode + corners ----------------
__global__ __launch_bounds__(256)
void k_select(const unsigned long long* __restrict__ cand, const int* __restrict__ cnt,
              const float* __restrict__ reg, const float* __restrict__ ang,
              const float* __restrict__ anchors,
              float* __restrict__ cor, float* __restrict__ area, int* __restrict__ lab,
              float* __restrict__ sc, int* __restrict__ val) {
#pragma clang fp contract(off)
    const int n = blockIdx.x;
    __shared__ unsigned long long key[CAP];
    int c = cnt[n];
    if (c > CAP) c = CAP;
    int S = 512;
    while (S < c) S <<= 1;     // S in {512..4096}, >= max(c, KTOP)
    for (int t = threadIdx.x; t < S; t += 256)
        key[t] = (t < c) ? cand[n * CAP + t] : 0ULL;
    __syncthreads();
    // bitonic sort ascending (largest at key[S-1])
    for (int k = 2; k <= S; k <<= 1) {
        for (int j = k >> 1; j > 0; j >>= 1) {
            for (int i = threadIdx.x; i < S; i += 256) {
                int l = i ^ j;
                if (l > i) {
                    unsigned long long a = key[i], b = key[l];
                    bool up = ((i & k) == 0);
                    if ((a > b) == up) { key[i] = b; key[l] = a; }
                }
            }
            __syncthreads();
        }
    }
    for (int r = threadIdx.x; r < KTOP; r += 256) {
        unsigned long long kk = key[S - 1 - r];
        int base = n * KTOP + r;
        if (kk == 0ULL) {
            val[base] = 0; sc[base] = 0.0f; lab[base] = 0; area[base] = 0.0f;
            for (int q = 0; q < 8; ++q) cor[base * 8 + q] = 0.0f;
            continue;
        }
        float topv = __uint_as_float((unsigned int)(kk >> 32));
        unsigned int idx = ~((unsigned int)kk);
        int loc = (int)(idx / 15u);
        int cl  = (int)(idx % 15u);
        // angle argmax (first max, like jnp.argmax)
        const float* ap = ang + ((size_t)n * NANG) * HW + loc;
        float best = ap[0]; int bi = 0;
        for (int b = 1; b < NANG; ++b) {
            float v2 = ap[(size_t)b * HW];
            if (v2 > best) { best = v2; bi = b; }
        }
        // decode
        const float* rp = reg + ((size_t)n * 4) * HW + loc;
        float dx = rp[0] / 10.0f;
        float dy = rp[HW] / 10.0f;
        float dw = rp[2 * (size_t)HW] / 5.0f;
        float dh = rp[3 * (size_t)HW] / 5.0f;
        dw = fminf(fmaxf(dw, -10.0f), 4.0f);
        dh = fminf(fmaxf(dh, -10.0f), 4.0f);
        const float* an = anchors + ((size_t)n * HW + loc) * 5;
        float acx = an[0], acy = an[1], aw = an[2], ah = an[3];
        float bcx = dx * aw + acx;
        float bcy = dy * ah + acy;
        float bw = aw * expf(dw);
        float bh = ah * expf(dh);
        float pa = (float)bi - 90.0f;
        float th = pa * (float)0.017453292519943295;
        float cth = cosf(th), sth = sinf(th);
        float hw2 = bw * 0.5f, hh2 = bh * 0.5f;
        const float oxs[4] = {1.0f, -1.0f, -1.0f, 1.0f};
        const float oys[4] = {1.0f, 1.0f, -1.0f, -1.0f};
        for (int q = 0; q < 4; ++q) {
            float ox = oxs[q] * hw2, oy = oys[q] * hh2;
            cor[base * 8 + 2 * q]     = bcx + ox * cth - oy * sth;
            cor[base * 8 + 2 * q + 1] = bcy + ox * sth + oy * cth;
        }
        val[base] = 1;
        sc[base] = sqrtf(topv);
        lab[base] = cl + 1;
        area[base] = bw * bh;
    }
}

// ---------------- rotated-quad intersection (Sutherland-Hodgman, mirrors ref) ----
__device__ float quad_inter_area(const float* c1x, const float* c1y,
                                 const float* c2x, const float* c2y) {
#pragma clang fp contract(off)
    float px[16], py[16], qx[16], qy[16];
    int n = 4;
    for (int i = 0; i < 4; ++i) { px[i] = c1x[i]; py[i] = c1y[i]; }
    for (int e = 0; e < 4; ++e) {
        float p1x = c2x[e], p1y = c2y[e];
        int e2 = (e + 1) & 3;
        float ex = c2x[e2] - p1x, ey = c2y[e2] - p1y;
        int m = 0;
        for (int i = 0; i < n && i < 8; ++i) {
            int j = (i == n - 1) ? 0 : i + 1;
            float cxi = px[i], cyi = py[i];
            float cxj = px[j], cyj = py[j];
            float dc = ex * (cyi - p1y) - ey * (cxi - p1x);
            float dn = ex * (cyj - p1y) - ey * (cxj - p1x);
            bool ic = (dc >= 0.0f), in2 = (dn >= 0.0f);
            if (ic) { if (m < 16) { qx[m] = cxi; qy[m] = cyi; } ++m; }
            if (ic != in2) {
                float denom = dc - dn;
                if (fabsf(denom) < 1e-8f) denom = 1e-8f;
                float tp = dc / denom;
                if (m < 16) { qx[m] = cxi + tp * (cxj - cxi); qy[m] = cyi + tp * (cyj - cyi); }
                ++m;
            }
        }
        n = m > 16 ? 16 : m;
        if (n == 0) return 0.0f;
        for (int i = 0; i < n; ++i) { px[i] = qx[i]; py[i] = qy[i]; }
    }
    float ssum = 0.0f;
    for (int i = 0; i < n; ++i) {
        int j = (i == n - 1) ? 0 : i + 1;
        ssum += px[i] * py[j] - px[j] * py[i];
    }
    return 0.5f * fabsf(ssum);
}

// ---------------- K4b: same-class pair IoU -> suppress bitmask ----------------
__global__ __launch_bounds__(256)
void k_pairs(const float* __restrict__ cor, const float* __restrict__ area,
             const int* __restrict__ lab, const int* __restrict__ val,
             unsigned int* __restrict__ sup) {
#pragma clang fp contract(off)
    const int n = blockIdx.y;
    const int i = blockIdx.x;            // row 0..KTOP-2
    const int base = n * KTOP;
    if (!val[base + i]) return;          // uniform across block
    const int li = lab[base + i];
    const float ai = area[base + i];
    float cix[4], ciy[4];
    for (int q = 0; q < 4; ++q) {
        cix[q] = cor[(base + i) * 8 + 2 * q];
        ciy[q] = cor[(base + i) * 8 + 2 * q + 1];
    }
    __shared__ unsigned int row[SUPW];
    if (threadIdx.x < SUPW) row[threadIdx.x] = 0;
    __syncthreads();
    for (int j = i + 1 + threadIdx.x; j < KTOP; j += 256) {
        if (val[base + j] && lab[base + j] == li) {
            float cjx[4], cjy[4];
            for (int q = 0; q < 4; ++q) {
                cjx[q] = cor[(base + j) * 8 + 2 * q];
                cjy[q] = cor[(base + j) * 8 + 2 * q + 1];
            }
            float inter = quad_inter_area(cix, ciy, cjx, cjy);
            float iou = inter / (ai + area[base + j] - inter + 1e-7f);
            if (iou > 0.4f) atomicOr(&row[j >> 5], 1u << (j & 31));
        }
    }
    __syncthreads();
    if (threadIdx.x < SUPW) sup[(size_t)(base + i) * SUPW + threadIdx.x] = row[threadIdx.x];
}

// ---------------- K4c: greedy NMS + top-100 output ----------------
__global__ __launch_bounds__(512)
void k_nms_out(const float* __restrict__ cor, const float* __restrict__ sc,
               const int* __restrict__ lab, const int* __restrict__ val,
               const unsigned int* __restrict__ sup, float* __restrict__ out) {
    const int n = blockIdx.x;
    __shared__ int keep[KTOP];
    __shared__ int order[POSTN];
    __shared__ int kcnt;
    const int tid = threadIdx.x;
    for (int t = tid; t < KTOP; t += 512) keep[t] = val[n * KTOP + t];
    __syncthreads();
    for (int i = 0; i < KTOP - 1; ++i) {
        if (keep[i]) {                         // uniform branch
            int j = i + 1 + tid;
            if (j < KTOP) {
                if ((sup[(size_t)(n * KTOP + i) * SUPW + (j >> 5)] >> (j & 31)) & 1u)
                    keep[j] = 0;
            }
            __syncthreads();
        }
    }
    __syncthreads();
    if (tid == 0) {
        int r = 0;
        for (int i = 0; i < KTOP && r < POSTN; ++i)
            if (keep[i]) order[r++] = i;
        kcnt = r;
    }
    __syncthreads();
    for (int t = tid; t < POSTN * 11; t += 512) {
        int r = t / 11, col = t % 11;
        float v = 0.0f;
        if (r < kcnt) {
            int i = order[r];
            int b = n * KTOP + i;
            if (col < 8)      v = cor[b * 8 + col];
            else if (col == 8) v = sc[b];
            else if (col == 9) v = (float)lab[b];
            else               v = 1.0f;
        }
        out[(n * POSTN + r) * 11 + col] = v;
    }
}

extern "C" void kernel_launch(void* const* d_in, const int* in_sizes, int n_in,
                              void* d_out, int out_size, void* d_ws, size_t ws_size,
                              hipStream_t stream) {
    const float* box_cls = (const float*)d_in[0];
    const float* box_reg = (const float*)d_in[1];
    const float* ctr     = (const float*)d_in[2];
    const float* ang     = (const float*)d_in[3];
    const float* anchors = (const float*)d_in[4];
    float* out = (float*)d_out;
    char* ws = (char*)d_ws;

    int* hist = (int*)(ws + HIST_OFF);
    int* cnt  = (int*)(ws + CNT_OFF);
    int* tbin = (int*)(ws + TBIN_OFF);
    unsigned int* sup = (unsigned int*)(ws + SUP_OFF);
    unsigned long long* cand = (unsigned long long*)(ws + CAND_OFF);
    float* cor  = (float*)(ws + COR_OFF);
    float* area = (float*)(ws + AREA_OFF);
    int* lab    = (int*)(ws + LAB_OFF);
    float* sc   = (float*)(ws + SC_OFF);
    int* val    = (int*)(ws + VAL_OFF);

    hipMemsetAsync(d_ws, 0, ZERO_BYTES, stream);
    k_hist   <<<dim3(HW / 256, NIMG), 256, 0, stream>>>(box_cls, ctr, hist);
    k_thresh <<<NIMG, 256, 0, stream>>>(hist, tbin);
    k_collect<<<dim3(HW / 256, NIMG), 256, 0, stream>>>(box_cls, ctr, tbin, cnt, cand);
    k_select <<<NIMG, 256, 0, stream>>>(cand, cnt, box_reg, ang, anchors,
                                        cor, area, lab, sc, val);
    k_pairs  <<<dim3(KTOP - 1, NIMG), 256, 0, stream>>>(cor, area, lab, val, sup);
    k_nms_out<<<NIMG, 512, 0, stream>>>(cor, sc, lab, val, sup, out);
}

// Round 3
// 402.364 us; speedup vs baseline: 1.0934x; 1.0934x over previous
//
#include <hip/hip_runtime.h>
#include <math.h>

#define NIMG 4
#define NCLS 15
#define HDIM 256
#define WDIM 256
#define HW (HDIM*WDIM)
#define NANG 90
#define KTOP 400
#define POSTN 100
#define NBINS 4096
#define CAP 4096

// ---- workspace layout (bytes) ----
// sizes: hist 4*4096*4=65536 | cnt 64 | tbin 64 | supT 4*7*7*64*8=100352
//        cand 4*4096*8=131072 | skey 4*400*8=12800 | cor 4*400*8*4=51200
//        area/lab/sc/val/ccx/ccy/crad 4*400*4=6400 each
#define HIST_OFF   0
#define CNT_OFF    65536
#define TBIN_OFF   65600
#define SUPT_OFF   65664
#define ZERO_BYTES 166016                 // = SUPT_OFF + 100352 (memset region end)
#define CAND_OFF   166016
#define SKEY_OFF   297088
#define COR_OFF    309888
#define AREA_OFF   361088
#define LAB_OFF    367488
#define SC_OFF     373888
#define VAL_OFF    380288
#define CCX_OFF    386688
#define CCY_OFF    393088
#define CRAD_OFF   399488                 // end 405888

__device__ __forceinline__ float sigmoidf(float x) {
    return 1.0f / (1.0f + expf(-x));
}

// ---------------- K1: histogram of comb scores ----------------
__global__ void k_hist(const float* __restrict__ cls, const float* __restrict__ ctr,
                       int* __restrict__ hist) {
    __shared__ int sh[NBINS];
    const int n = blockIdx.y;
    const int p = blockIdx.x * 256 + threadIdx.x;
    for (int b = threadIdx.x; b < NBINS; b += 256) sh[b] = 0;
    __syncthreads();
    float cv = sigmoidf(ctr[n * HW + p]);
    for (int j = 0; j < NCLS; ++j) {
        float s = sigmoidf(cls[(n * NCLS + j) * HW + p]);
        if (s > 0.05f) {
            float comb = s * cv;
            int b = (int)(comb * 4096.0f);
            b = b < 0 ? 0 : (b > NBINS - 1 ? NBINS - 1 : b);
            atomicAdd(&sh[b], 1);
        }
    }
    __syncthreads();
    for (int b = threadIdx.x; b < NBINS; b += 256) {
        int v = sh[b];
        if (v) atomicAdd(&hist[n * NBINS + b], v);
    }
}

// ---------------- K2: find threshold bin (>= 400 above) ----------------
__global__ void k_thresh(const int* __restrict__ hist, int* __restrict__ tbin) {
    const int n = blockIdx.x;
    __shared__ int sh[NBINS];
    __shared__ int part[256];
    for (int b = threadIdx.x; b < NBINS; b += 256) sh[b] = hist[n * NBINS + b];
    __syncthreads();
    int s = 0;
    int base = threadIdx.x * 16;
    for (int b = 0; b < 16; ++b) s += sh[base + b];
    part[threadIdx.x] = s;
    __syncthreads();
    if (threadIdx.x == 0) {
        int acc = 0, seg = -1, above = 0;
        for (int sg = 255; sg >= 0; --sg) {
            int ps = part[sg];
            if (acc + ps >= KTOP) { seg = sg; above = acc; break; }
            acc += ps;
        }
        int t = 0;
        if (seg >= 0) {
            int a2 = above;
            t = seg * 16;
            for (int b = seg * 16 + 15; b >= seg * 16; --b) {
                a2 += sh[b];
                if (a2 >= KTOP) { t = b; break; }
            }
        }
        tbin[n] = t;
    }
}

// ---------------- K3: collect candidates with bin >= t ----------------
__global__ void k_collect(const float* __restrict__ cls, const float* __restrict__ ctr,
                          const int* __restrict__ tbin, int* __restrict__ cnt,
                          unsigned long long* __restrict__ cand) {
    const int n = blockIdx.y;
    const int p = blockIdx.x * 256 + threadIdx.x;
    const int t = tbin[n];
    float cv = sigmoidf(ctr[n * HW + p]);
    for (int j = 0; j < NCLS; ++j) {
        float s = sigmoidf(cls[(n * NCLS + j) * HW + p]);
        if (s > 0.05f) {
            float comb = s * cv;
            int b = (int)(comb * 4096.0f);
            b = b < 0 ? 0 : (b > NBINS - 1 ? NBINS - 1 : b);
            if (b >= t) {
                int pos = atomicAdd(&cnt[n], 1);
                if (pos < CAP) {
                    unsigned int fb = __float_as_uint(comb);
                    unsigned int idx = (unsigned int)(p * NCLS + j);
                    cand[n * CAP + pos] =
                        ((unsigned long long)fb << 32) | (unsigned long long)(~idx);
                }
            }
        }
    }
}

// ---------------- K4: single-wave bitonic sort -> top-400 keys ----------------
__global__ __launch_bounds__(64)
void k_select(const unsigned long long* __restrict__ cand, const int* __restrict__ cnt,
              unsigned long long* __restrict__ skey) {
    const int n = blockIdx.x;
    __shared__ unsigned long long key[CAP];
    int c = cnt[n];
    if (c > CAP) c = CAP;
    int S = 512;
    while (S < c) S <<= 1;     // S in {512..4096}, >= max(c, KTOP)
    for (int t = threadIdx.x; t < S; t += 64)
        key[t] = (t < c) ? cand[n * CAP + t] : 0ULL;
    __syncthreads();           // single-wave workgroup: barrier is cheap
    for (int k = 2; k <= S; k <<= 1) {
        for (int j = k >> 1; j > 0; j >>= 1) {
            for (int i = threadIdx.x; i < S; i += 64) {
                int l = i ^ j;
                if (l > i) {
                    unsigned long long a = key[i], b = key[l];
                    bool up = ((i & k) == 0);
                    if ((a > b) == up) { key[i] = b; key[l] = a; }
                }
            }
            __syncthreads();
        }
    }
    for (int r = threadIdx.x; r < KTOP; r += 64)
        skey[n * KTOP + r] = key[S - 1 - r];
}

// ---------------- K5: per-candidate decode (one wave each) ----------------
__global__ __launch_bounds__(64)
void k_decode(const unsigned long long* __restrict__ skey,
              const float* __restrict__ reg, const float* __restrict__ ang,
              const float* __restrict__ anchors,
              float* __restrict__ cor, float* __restrict__ area, int* __restrict__ lab,
              float* __restrict__ sc, int* __restrict__ val,
              float* __restrict__ ccx, float* __restrict__ ccy, float* __restrict__ crad) {
#pragma clang fp contract(off)
    const int r = blockIdx.x;
    const int n = blockIdx.y;
    const int l = threadIdx.x;
    const int base = n * KTOP + r;
    unsigned long long kk = skey[base];
    if (kk == 0ULL) {
        if (l == 0) {
            val[base] = 0; sc[base] = 0.0f; lab[base] = 0; area[base] = 0.0f;
            ccx[base] = 0.0f; ccy[base] = 0.0f; crad[base] = 0.0f;
            for (int q = 0; q < 8; ++q) cor[base * 8 + q] = 0.0f;
        }
        return;
    }
    unsigned int idx = ~((unsigned int)kk);
    int loc = (int)(idx / 15u);
    // angle argmax (first max) across the wave
    const float* ap = ang + ((size_t)n * NANG) * HW + loc;
    float bv = -INFINITY; int bb = 1000;
    for (int b = l; b < NANG; b += 64) {
        float v = ap[(size_t)b * HW];
        if (v > bv) { bv = v; bb = b; }   // b ascending per lane: keeps first max
    }
    for (int off = 32; off > 0; off >>= 1) {
        float ov = __shfl_down(bv, off);
        int   ob = __shfl_down(bb, off);
        if (ov > bv || (ov == bv && ob < bb)) { bv = ov; bb = ob; }
    }
    if (l == 0) {
        int cl = (int)(idx % 15u);
        float topv = __uint_as_float((unsigned int)(kk >> 32));
        const float* rp = reg + ((size_t)n * 4) * HW + loc;
        float dx = rp[0] / 10.0f;
        float dy = rp[HW] / 10.0f;
        float dw = rp[2 * (size_t)HW] / 5.0f;
        float dh = rp[3 * (size_t)HW] / 5.0f;
        dw = fminf(fmaxf(dw, -10.0f), 4.0f);
        dh = fminf(fmaxf(dh, -10.0f), 4.0f);
        const float* an = anchors + ((size_t)n * HW + loc) * 5;
        float acx = an[0], acy = an[1], aw = an[2], ah = an[3];
        float bcx = dx * aw + acx;
        float bcy = dy * ah + acy;
        float bw = aw * expf(dw);
        float bh = ah * expf(dh);
        float pa = (float)bb - 90.0f;
        float th = pa * (float)0.017453292519943295;
        float cth = cosf(th), sth = sinf(th);
        float hw2 = bw * 0.5f, hh2 = bh * 0.5f;
        const float oxs[4] = {1.0f, -1.0f, -1.0f, 1.0f};
        const float oys[4] = {1.0f, 1.0f, -1.0f, -1.0f};
        for (int q = 0; q < 4; ++q) {
            float ox = oxs[q] * hw2, oy = oys[q] * hh2;
            cor[base * 8 + 2 * q]     = bcx + ox * cth - oy * sth;
            cor[base * 8 + 2 * q + 1] = bcy + ox * sth + oy * cth;
        }
        val[base] = 1;
        sc[base] = sqrtf(topv);
        lab[base] = cl + 1;
        area[base] = bw * bh;
        ccx[base] = bcx; ccy[base] = bcy;
        crad[base] = 0.5f * sqrtf(bw * bw + bh * bh);
    }
}

// ---- register-resident dynamic-index helpers (avoid scratch) ----
__device__ __forceinline__ float arr_get8(const float* a, int idx) {
    float r = a[0];
#pragma unroll
    for (int s = 1; s < 8; ++s) r = (s == idx) ? a[s] : r;
    return r;
}
__device__ __forceinline__ void arr_set8(float* a, int idx, float v) {
#pragma unroll
    for (int s = 0; s < 8; ++s) a[s] = (s == idx) ? v : a[s];
}

// ---------------- rotated-quad intersection (Sutherland-Hodgman, mirrors ref) ----
__device__ float quad_inter_area(const float* c1x, const float* c1y,
                                 const float* c2x, const float* c2y) {
#pragma clang fp contract(off)
    float px[8], py[8], qx[8], qy[8];
    int n = 4;
#pragma unroll
    for (int i = 0; i < 8; ++i) { px[i] = (i < 4) ? c1x[i] : 0.0f;
                                  py[i] = (i < 4) ? c1y[i] : 0.0f;
                                  qx[i] = 0.0f; qy[i] = 0.0f; }
#pragma unroll
    for (int e = 0; e < 4; ++e) {
        float p1x = c2x[e], p1y = c2y[e];
        int e2 = (e + 1) & 3;
        float ex = c2x[e2] - p1x, ey = c2y[e2] - p1y;
        int m = 0;
#pragma unroll
        for (int i = 0; i < 8; ++i) {
            if (i < n) {
                int j = (i == n - 1) ? 0 : i + 1;
                float cxi = px[i], cyi = py[i];
                float cxj = arr_get8(px, j), cyj = arr_get8(py, j);
                float dc = ex * (cyi - p1y) - ey * (cxi - p1x);
                float dn = ex * (cyj - p1y) - ey * (cxj - p1x);
                bool ic = (dc >= 0.0f), in2 = (dn >= 0.0f);
                if (ic) { arr_set8(qx, m, cxi); arr_set8(qy, m, cyi); ++m; }
                if (ic != in2) {
                    float denom = dc - dn;
                    if (fabsf(denom) < 1e-8f) denom = 1e-8f;
                    float tp = dc / denom;
                    arr_set8(qx, m, cxi + tp * (cxj - cxi));
                    arr_set8(qy, m, cyi + tp * (cyj - cyi));
                    ++m;
                }
            }
        }
        n = m;
        if (n == 0) return 0.0f;
#pragma unroll
        for (int i = 0; i < 8; ++i) { px[i] = qx[i]; py[i] = qy[i]; }
    }
    float ssum = 0.0f;
#pragma unroll
    for (int i = 0; i < 8; ++i) {
        if (i < n) {
            int j = (i == n - 1) ? 0 : i + 1;
            ssum += px[i] * arr_get8(py, j) - arr_get8(px, j) * py[i];
        }
    }
    return 0.5f * fabsf(ssum);
}

// ---------------- K6: same-class pair IoU -> transposed suppress bits ----------------
__global__ __launch_bounds__(256)
void k_pairs(const float* __restrict__ cor, const float* __restrict__ area,
             const int* __restrict__ lab,
             const float* __restrict__ ccx, const float* __restrict__ ccy,
             const float* __restrict__ crad,
             unsigned long long* __restrict__ supT) {
#pragma clang fp contract(off)
    const int n = blockIdx.x;
    const int tid = threadIdx.x;
    const int base = n * KTOP;
    __shared__ float s_cor[KTOP * 8];
    __shared__ float s_cx[KTOP], s_cy[KTOP], s_r[KTOP], s_area[KTOP];
    __shared__ int   s_lab[KTOP];
    for (int t = tid; t < KTOP * 8; t += 256) s_cor[t] = cor[base * 8 + t];
    for (int t = tid; t < KTOP; t += 256) {
        s_cx[t] = ccx[base + t]; s_cy[t] = ccy[base + t];
        s_r[t]  = crad[base + t]; s_area[t] = area[base + t];
        s_lab[t] = lab[base + t];
    }
    __syncthreads();
    for (int p = tid; p < KTOP * KTOP; p += 256) {
        int i = p / KTOP;
        int j = p - i * KTOP;
        if (j <= i) continue;
        int li = s_lab[i];
        if (li == 0 || s_lab[j] != li) continue;
        float dx = s_cx[i] - s_cx[j], dy = s_cy[i] - s_cy[j];
        float rr = s_r[i] + s_r[j];
        if (dx * dx + dy * dy > rr * rr) continue;   // provably disjoint -> inter==0
        float cix[4], ciy[4], cjx[4], cjy[4];
        for (int q = 0; q < 4; ++q) {
            cix[q] = s_cor[i * 8 + 2 * q]; ciy[q] = s_cor[i * 8 + 2 * q + 1];
            cjx[q] = s_cor[j * 8 + 2 * q]; cjy[q] = s_cor[j * 8 + 2 * q + 1];
        }
        float inter = quad_inter_area(cix, ciy, cjx, cjy);
        float iou = inter / (s_area[i] + s_area[j] - inter + 1e-7f);
        if (iou > 0.4f) {
            // row i suppresses column j: bit (i&63) of supT[n][j>>6][i>>6][j&63]
            atomicOr(&supT[((size_t)(n * 7 + (j >> 6)) * 7 + (i >> 6)) * 64 + (j & 63)],
                     1ULL << (i & 63));
        }
    }
}

// ---------------- K7: single-wave register-resident greedy NMS + output ----------------
__global__ __launch_bounds__(64)
void k_nms_out(const unsigned long long* __restrict__ supT,
               const int* __restrict__ val,
               const float* __restrict__ cor, const float* __restrict__ sc,
               const int* __restrict__ lab, float* __restrict__ out) {
    const int n = blockIdx.x;
    const int l = threadIdx.x;
    // lane l owns columns (candidates) l, l+64, ..., l+384; bit t of `removed`
    unsigned removed = 0;
#pragma unroll
    for (int t = 0; t < 7; ++t) {
        int r = 64 * t + l;
        int v = (r < KTOP) ? val[n * KTOP + r] : 0;
        if (!v) removed |= (1u << t);
    }
    // load transposed suppression matrix: cm[t][rb] bit ib = row (64*rb+ib) suppresses col (64*t+l)
    unsigned long long cm[7][7];
#pragma unroll
    for (int t = 0; t < 7; ++t)
#pragma unroll
        for (int rb = 0; rb < 7; ++rb)
            cm[t][rb] = supT[((size_t)(n * 7 + t) * 7 + rb) * 64 + l];
    // serial greedy scan, all in registers
#pragma unroll
    for (int rb = 0; rb < 7; ++rb) {
        const int lim = (rb == 6) ? (KTOP - 384) : 64;
        for (int ib = 0; ib < lim; ++ib) {
            unsigned rm = (unsigned)__builtin_amdgcn_readlane((int)removed, ib);
            if (!((rm >> rb) & 1u)) {   // candidate 64*rb+ib kept -> apply its suppressions
                removed |= ((unsigned)((cm[0][rb] >> ib) & 1ULL));
                removed |= ((unsigned)((cm[1][rb] >> ib) & 1ULL)) << 1;
                removed |= ((unsigned)((cm[2][rb] >> ib) & 1ULL)) << 2;
                removed |= ((unsigned)((cm[3][rb] >> ib) & 1ULL)) << 3;
                removed |= ((unsigned)((cm[4][rb] >> ib) & 1ULL)) << 4;
                removed |= ((unsigned)((cm[5][rb] >> ib) & 1ULL)) << 5;
                removed |= ((unsigned)((cm[6][rb] >> ib) & 1ULL)) << 6;
            }
        }
    }
    // rank kept candidates in index order, collect first 100
    __shared__ int order[POSTN];
    int rank = 0;
#pragma unroll
    for (int t = 0; t < 7; ++t) {
        bool kb = !((removed >> t) & 1u) && (64 * t + l < KTOP);
        unsigned long long m = __ballot(kb);
        int my = rank + __popcll(m & ((1ULL << l) - 1ULL));
        if (kb && my < POSTN) order[my] = 64 * t + l;
        rank += __popcll(m);
    }
    int kcnt = rank < POSTN ? rank : POSTN;
    __syncthreads();   // single wave: cheap; makes order[] visible
    for (int e = l; e < POSTN * 11; e += 64) {
        int r = e / 11, c = e - r * 11;
        float v = 0.0f;
        if (r < kcnt) {
            int i = order[r];
            int b = n * KTOP + i;
            if (c < 8)       v = cor[b * 8 + c];
            else if (c == 8) v = sc[b];
            else if (c == 9) v = (float)lab[b];
            else             v = 1.0f;
        }
        out[(n * POSTN + r) * 11 + c] = v;
    }
}

extern "C" void kernel_launch(void* const* d_in, const int* in_sizes, int n_in,
                              void* d_out, int out_size, void* d_ws, size_t ws_size,
                              hipStream_t stream) {
    const float* box_cls = (const float*)d_in[0];
    const float* box_reg = (const float*)d_in[1];
    const float* ctr     = (const float*)d_in[2];
    const float* ang     = (const float*)d_in[3];
    const float* anchors = (const float*)d_in[4];
    float* out = (float*)d_out;
    char* ws = (char*)d_ws;

    int* hist = (int*)(ws + HIST_OFF);
    int* cnt  = (int*)(ws + CNT_OFF);
    int* tbin = (int*)(ws + TBIN_OFF);
    unsigned long long* supT = (unsigned long long*)(ws + SUPT_OFF);
    unsigned long long* cand = (unsigned long long*)(ws + CAND_OFF);
    unsigned long long* skey = (unsigned long long*)(ws + SKEY_OFF);
    float* cor  = (float*)(ws + COR_OFF);
    float* area = (float*)(ws + AREA_OFF);
    int* lab    = (int*)(ws + LAB_OFF);
    float* sc   = (float*)(ws + SC_OFF);
    int* val    = (int*)(ws + VAL_OFF);
    float* ccx  = (float*)(ws + CCX_OFF);
    float* ccy  = (float*)(ws + CCY_OFF);
    float* crad = (float*)(ws + CRAD_OFF);

    hipMemsetAsync(d_ws, 0, ZERO_BYTES, stream);
    k_hist   <<<dim3(HW / 256, NIMG), 256, 0, stream>>>(box_cls, ctr, hist);
    k_thresh <<<NIMG, 256, 0, stream>>>(hist, tbin);
    k_collect<<<dim3(HW / 256, NIMG), 256, 0, stream>>>(box_cls, ctr, tbin, cnt, cand);
    k_select <<<NIMG, 64, 0, stream>>>(cand, cnt, skey);
    k_decode <<<dim3(KTOP, NIMG), 64, 0, stream>>>(skey, box_reg, ang, anchors,
                                                   cor, area, lab, sc, val, ccx, ccy, crad);
    k_pairs  <<<NIMG, 256, 0, stream>>>(cor, area, lab, ccx, ccy, crad, supT);
    k_nms_out<<<NIMG, 64, 0, stream>>>(supT, val, cor, sc, lab, out);
}

// Round 4
// 268.377 us; speedup vs baseline: 1.6392x; 1.4992x over previous
//
#include <hip/hip_runtime.h>
#include <math.h>

#define NIMG 4
#define NCLS 15
#define HDIM 256
#define WDIM 256
#define HW (HDIM*WDIM)
#define NANG 90
#define KTOP 400
#define POSTN 100
#define NBINS 4096
#define CAP 4096
#define PAIRCAP 81920   // >= C(400,2): compacted pair list can never overflow

// ---- workspace layout (bytes) ----
// zeroed region: hist 65536 | cnt 64 | tbin 64 | pcnt 64 | supT 4*7*7*64*8=100352
#define HIST_OFF   0
#define CNT_OFF    65536
#define TBIN_OFF   65600
#define PCNT_OFF   65664
#define SUPT_OFF   65728
#define ZERO_BYTES 166080                 // = SUPT_OFF + 100352
#define CAND_OFF   166080                 // 4*4096*8 = 131072
#define SKEY_OFF   297152                 // 4*400*8 = 12800
#define COR_OFF    309952                 // 4*400*8*4 = 51200
#define AREA_OFF   361152                 // 6400 each below
#define LAB_OFF    367552
#define SC_OFF     373952
#define VAL_OFF    380352
#define CCX_OFF    386752
#define CCY_OFF    393152
#define CRAD_OFF   399552
#define PAIRS_OFF  405952                 // 4*81920*4 = 1310720 -> end 1716672

__device__ __forceinline__ float sigmoidf(float x) {
    return 1.0f / (1.0f + expf(-x));
}

// ---------------- K1: histogram of comb scores ----------------
__global__ void k_hist(const float* __restrict__ cls, const float* __restrict__ ctr,
                       int* __restrict__ hist) {
    __shared__ int sh[NBINS];
    const int n = blockIdx.y;
    const int p = blockIdx.x * 256 + threadIdx.x;
    for (int b = threadIdx.x; b < NBINS; b += 256) sh[b] = 0;
    __syncthreads();
    float cv = sigmoidf(ctr[n * HW + p]);
    for (int j = 0; j < NCLS; ++j) {
        float s = sigmoidf(cls[(n * NCLS + j) * HW + p]);
        if (s > 0.05f) {
            float comb = s * cv;
            int b = (int)(comb * 4096.0f);
            b = b < 0 ? 0 : (b > NBINS - 1 ? NBINS - 1 : b);
            atomicAdd(&sh[b], 1);
        }
    }
    __syncthreads();
    for (int b = threadIdx.x; b < NBINS; b += 256) {
        int v = sh[b];
        if (v) atomicAdd(&hist[n * NBINS + b], v);
    }
}

// ---------------- K2: find threshold bin (>= 400 above) ----------------
__global__ void k_thresh(const int* __restrict__ hist, int* __restrict__ tbin) {
    const int n = blockIdx.x;
    __shared__ int sh[NBINS];
    __shared__ int part[256];
    for (int b = threadIdx.x; b < NBINS; b += 256) sh[b] = hist[n * NBINS + b];
    __syncthreads();
    int s = 0;
    int base = threadIdx.x * 16;
    for (int b = 0; b < 16; ++b) s += sh[base + b];
    part[threadIdx.x] = s;
    __syncthreads();
    if (threadIdx.x == 0) {
        int acc = 0, seg = -1, above = 0;
        for (int sg = 255; sg >= 0; --sg) {
            int ps = part[sg];
            if (acc + ps >= KTOP) { seg = sg; above = acc; break; }
            acc += ps;
        }
        int t = 0;
        if (seg >= 0) {
            int a2 = above;
            t = seg * 16;
            for (int b = seg * 16 + 15; b >= seg * 16; --b) {
                a2 += sh[b];
                if (a2 >= KTOP) { t = b; break; }
            }
        }
        tbin[n] = t;
    }
}

// ---------------- K3: collect candidates with bin >= t ----------------
__global__ void k_collect(const float* __restrict__ cls, const float* __restrict__ ctr,
                          const int* __restrict__ tbin, int* __restrict__ cnt,
                          unsigned long long* __restrict__ cand) {
    const int n = blockIdx.y;
    const int p = blockIdx.x * 256 + threadIdx.x;
    const int t = tbin[n];
    float cv = sigmoidf(ctr[n * HW + p]);
    for (int j = 0; j < NCLS; ++j) {
        float s = sigmoidf(cls[(n * NCLS + j) * HW + p]);
        if (s > 0.05f) {
            float comb = s * cv;
            int b = (int)(comb * 4096.0f);
            b = b < 0 ? 0 : (b > NBINS - 1 ? NBINS - 1 : b);
            if (b >= t) {
                int pos = atomicAdd(&cnt[n], 1);
                if (pos < CAP) {
                    unsigned int fb = __float_as_uint(comb);
                    unsigned int idx = (unsigned int)(p * NCLS + j);
                    cand[n * CAP + pos] =
                        ((unsigned long long)fb << 32) | (unsigned long long)(~idx);
                }
            }
        }
    }
}

// ---------------- K4: bitonic sort -> top-400 keys ----------------
__global__ __launch_bounds__(256)
void k_select(const unsigned long long* __restrict__ cand, const int* __restrict__ cnt,
              unsigned long long* __restrict__ skey) {
    const int n = blockIdx.x;
    __shared__ unsigned long long key[CAP];
    int c = cnt[n];
    if (c > CAP) c = CAP;
    int S = 512;
    while (S < c) S <<= 1;     // S in {512..4096}, >= max(c, KTOP)
    for (int t = threadIdx.x; t < S; t += 256)
        key[t] = (t < c) ? cand[n * CAP + t] : 0ULL;
    __syncthreads();
    for (int k = 2; k <= S; k <<= 1) {
        for (int j = k >> 1; j > 0; j >>= 1) {
            for (int i = threadIdx.x; i < S; i += 256) {
                int l = i ^ j;
                if (l > i) {
                    unsigned long long a = key[i], b = key[l];
                    bool up = ((i & k) == 0);
                    if ((a > b) == up) { key[i] = b; key[l] = a; }
                }
            }
            __syncthreads();
        }
    }
    for (int r = threadIdx.x; r < KTOP; r += 256)
        skey[n * KTOP + r] = key[S - 1 - r];
}

// ---------------- K5: per-candidate decode (one wave each) ----------------
__global__ __launch_bounds__(64)
void k_decode(const unsigned long long* __restrict__ skey,
              const float* __restrict__ reg, const float* __restrict__ ang,
              const float* __restrict__ anchors,
              float* __restrict__ cor, float* __restrict__ area, int* __restrict__ lab,
              float* __restrict__ sc, int* __restrict__ val,
              float* __restrict__ ccx, float* __restrict__ ccy, float* __restrict__ crad) {
#pragma clang fp contract(off)
    const int r = blockIdx.x;
    const int n = blockIdx.y;
    const int l = threadIdx.x;
    const int base = n * KTOP + r;
    unsigned long long kk = skey[base];
    if (kk == 0ULL) {
        if (l == 0) {
            val[base] = 0; sc[base] = 0.0f; lab[base] = 0; area[base] = 0.0f;
            ccx[base] = 0.0f; ccy[base] = 0.0f; crad[base] = 0.0f;
            for (int q = 0; q < 8; ++q) cor[base * 8 + q] = 0.0f;
        }
        return;
    }
    unsigned int idx = ~((unsigned int)kk);
    int loc = (int)(idx / 15u);
    // angle argmax (first max) across the wave
    const float* ap = ang + ((size_t)n * NANG) * HW + loc;
    float bv = -INFINITY; int bb = 1000;
    for (int b = l; b < NANG; b += 64) {
        float v = ap[(size_t)b * HW];
        if (v > bv) { bv = v; bb = b; }   // b ascending per lane: keeps first max
    }
    for (int off = 32; off > 0; off >>= 1) {
        float ov = __shfl_down(bv, off);
        int   ob = __shfl_down(bb, off);
        if (ov > bv || (ov == bv && ob < bb)) { bv = ov; bb = ob; }
    }
    if (l == 0) {
        int cl = (int)(idx % 15u);
        float topv = __uint_as_float((unsigned int)(kk >> 32));
        const float* rp = reg + ((size_t)n * 4) * HW + loc;
        float dx = rp[0] / 10.0f;
        float dy = rp[HW] / 10.0f;
        float dw = rp[2 * (size_t)HW] / 5.0f;
        float dh = rp[3 * (size_t)HW] / 5.0f;
        dw = fminf(fmaxf(dw, -10.0f), 4.0f);
        dh = fminf(fmaxf(dh, -10.0f), 4.0f);
        const float* an = anchors + ((size_t)n * HW + loc) * 5;
        float acx = an[0], acy = an[1], aw = an[2], ah = an[3];
        float bcx = dx * aw + acx;
        float bcy = dy * ah + acy;
        float bw = aw * expf(dw);
        float bh = ah * expf(dh);
        float pa = (float)bb - 90.0f;
        float th = pa * (float)0.017453292519943295;
        float cth = cosf(th), sth = sinf(th);
        float hw2 = bw * 0.5f, hh2 = bh * 0.5f;
        const float oxs[4] = {1.0f, -1.0f, -1.0f, 1.0f};
        const float oys[4] = {1.0f, 1.0f, -1.0f, -1.0f};
        for (int q = 0; q < 4; ++q) {
            float ox = oxs[q] * hw2, oy = oys[q] * hh2;
            cor[base * 8 + 2 * q]     = bcx + ox * cth - oy * sth;
            cor[base * 8 + 2 * q + 1] = bcy + ox * sth + oy * cth;
        }
        val[base] = 1;
        sc[base] = sqrtf(topv);
        lab[base] = cl + 1;
        area[base] = bw * bh;
        ccx[base] = bcx; ccy[base] = bcy;
        crad[base] = 0.5f * sqrtf(bw * bw + bh * bh);
    }
}

// ---- register-resident dynamic-index helpers (avoid scratch) ----
__device__ __forceinline__ float arr_get8(const float* a, int idx) {
    float r = a[0];
#pragma unroll
    for (int s = 1; s < 8; ++s) r = (s == idx) ? a[s] : r;
    return r;
}
__device__ __forceinline__ void arr_set8(float* a, int idx, float v) {
#pragma unroll
    for (int s = 0; s < 8; ++s) a[s] = (s == idx) ? v : a[s];
}

// ---------------- rotated-quad intersection (Sutherland-Hodgman, mirrors ref) ----
__device__ float quad_inter_area(const float* c1x, const float* c1y,
                                 const float* c2x, const float* c2y) {
#pragma clang fp contract(off)
    float px[8], py[8], qx[8], qy[8];
    int n = 4;
#pragma unroll
    for (int i = 0; i < 8; ++i) { px[i] = (i < 4) ? c1x[i] : 0.0f;
                                  py[i] = (i < 4) ? c1y[i] : 0.0f;
                                  qx[i] = 0.0f; qy[i] = 0.0f; }
#pragma unroll
    for (int e = 0; e < 4; ++e) {
        float p1x = c2x[e], p1y = c2y[e];
        int e2 = (e + 1) & 3;
        float ex = c2x[e2] - p1x, ey = c2y[e2] - p1y;
        int m = 0;
#pragma unroll
        for (int i = 0; i < 8; ++i) {
            if (i < n) {
                int j = (i == n - 1) ? 0 : i + 1;
                float cxi = px[i], cyi = py[i];
                float cxj = arr_get8(px, j), cyj = arr_get8(py, j);
                float dc = ex * (cyi - p1y) - ey * (cxi - p1x);
                float dn = ex * (cyj - p1y) - ey * (cxj - p1x);
                bool ic = (dc >= 0.0f), in2 = (dn >= 0.0f);
                if (ic) { arr_set8(qx, m, cxi); arr_set8(qy, m, cyi); ++m; }
                if (ic != in2) {
                    float denom = dc - dn;
                    if (fabsf(denom) < 1e-8f) denom = 1e-8f;
                    float tp = dc / denom;
                    arr_set8(qx, m, cxi + tp * (cxj - cxi));
                    arr_set8(qy, m, cyi + tp * (cyj - cyi));
                    ++m;
                }
            }
        }
        n = m;
        if (n == 0) return 0.0f;
#pragma unroll
        for (int i = 0; i < 8; ++i) { px[i] = qx[i]; py[i] = qy[i]; }
    }
    float ssum = 0.0f;
#pragma unroll
    for (int i = 0; i < 8; ++i) {
        if (i < n) {
            int j = (i == n - 1) ? 0 : i + 1;
            ssum += px[i] * arr_get8(py, j) - arr_get8(px, j) * py[i];
        }
    }
    return 0.5f * fabsf(ssum);
}

// ---------------- K6a: compact same-class, radius-overlapping pairs ----------------
__global__ __launch_bounds__(256)
void k_prefilter(const int* __restrict__ lab,
                 const float* __restrict__ ccx, const float* __restrict__ ccy,
                 const float* __restrict__ crad,
                 int* __restrict__ pcnt, int* __restrict__ pairs) {
    const int n = blockIdx.y;
    const int p = blockIdx.x * 256 + threadIdx.x;
    if (p >= KTOP * KTOP) return;
    const int i = p / KTOP;
    const int j = p - i * KTOP;
    if (j <= i) return;
    const int base = n * KTOP;
    const int li = lab[base + i];
    if (li == 0 || lab[base + j] != li) return;
    float dx = ccx[base + i] - ccx[base + j];
    float dy = ccy[base + i] - ccy[base + j];
    float rr = crad[base + i] + crad[base + j];
    if (dx * dx + dy * dy > rr * rr) return;   // provably disjoint -> inter==0 -> iou==0
    int pos = atomicAdd(&pcnt[n], 1);
    if (pos < PAIRCAP) pairs[n * PAIRCAP + pos] = (i << 16) | j;
}

// ---------------- K6b: one thread per surviving pair -> IoU -> suppress bits ----
__global__ __launch_bounds__(256)
void k_iou(const int* __restrict__ pcnt, const int* __restrict__ pairs,
           const float* __restrict__ cor, const float* __restrict__ area,
           unsigned long long* __restrict__ supT) {
#pragma clang fp contract(off)
    const int n = blockIdx.y;
    int c = pcnt[n];
    if (c > PAIRCAP) c = PAIRCAP;
    const int t = blockIdx.x * 256 + threadIdx.x;
    if (t >= c) return;
    const int pr = pairs[n * PAIRCAP + t];
    const int i = pr >> 16;
    const int j = pr & 0xffff;
    const int base = n * KTOP;
    float cix[4], ciy[4], cjx[4], cjy[4];
    for (int q = 0; q < 4; ++q) {
        cix[q] = cor[(base + i) * 8 + 2 * q]; ciy[q] = cor[(base + i) * 8 + 2 * q + 1];
        cjx[q] = cor[(base + j) * 8 + 2 * q]; cjy[q] = cor[(base + j) * 8 + 2 * q + 1];
    }
    float inter = quad_inter_area(cix, ciy, cjx, cjy);
    float iou = inter / (area[base + i] + area[base + j] - inter + 1e-7f);
    if (iou > 0.4f) {
        // row i suppresses column j: bit (i&63) of supT[n][j>>6][i>>6][j&63]
        atomicOr(&supT[((size_t)(n * 7 + (j >> 6)) * 7 + (i >> 6)) * 64 + (j & 63)],
                 1ULL << (i & 63));
    }
}

// ---------------- K7: single-wave register-resident greedy NMS + output ----------------
__global__ __launch_bounds__(64)
void k_nms_out(const unsigned long long* __restrict__ supT,
               const int* __restrict__ val,
               const float* __restrict__ cor, const float* __restrict__ sc,
               const int* __restrict__ lab, float* __restrict__ out) {
    const int n = blockIdx.x;
    const int l = threadIdx.x;
    // lane l owns columns (candidates) l, l+64, ..., l+384; bit t of `removed`
    unsigned removed = 0;
#pragma unroll
    for (int t = 0; t < 7; ++t) {
        int r = 64 * t + l;
        int v = (r < KTOP) ? val[n * KTOP + r] : 0;
        if (!v) removed |= (1u << t);
    }
    // cm[t][rb] bit ib = row (64*rb+ib) suppresses col (64*t+l)
    unsigned long long cm[7][7];
#pragma unroll
    for (int t = 0; t < 7; ++t)
#pragma unroll
        for (int rb = 0; rb < 7; ++rb)
            cm[t][rb] = supT[((size_t)(n * 7 + t) * 7 + rb) * 64 + l];
    // serial greedy scan, all in registers
#pragma unroll
    for (int rb = 0; rb < 7; ++rb) {
        const int lim = (rb == 6) ? (KTOP - 384) : 64;
        for (int ib = 0; ib < lim; ++ib) {
            unsigned rm = (unsigned)__builtin_amdgcn_readlane((int)removed, ib);
            if (!((rm >> rb) & 1u)) {   // candidate 64*rb+ib kept -> apply its suppressions
                removed |= ((unsigned)((cm[0][rb] >> ib) & 1ULL));
                removed |= ((unsigned)((cm[1][rb] >> ib) & 1ULL)) << 1;
                removed |= ((unsigned)((cm[2][rb] >> ib) & 1ULL)) << 2;
                removed |= ((unsigned)((cm[3][rb] >> ib) & 1ULL)) << 3;
                removed |= ((unsigned)((cm[4][rb] >> ib) & 1ULL)) << 4;
                removed |= ((unsigned)((cm[5][rb] >> ib) & 1ULL)) << 5;
                removed |= ((unsigned)((cm[6][rb] >> ib) & 1ULL)) << 6;
            }
        }
    }
    // rank kept candidates in index order, collect first 100
    __shared__ int order[POSTN];
    int rank = 0;
#pragma unroll
    for (int t = 0; t < 7; ++t) {
        bool kb = !((removed >> t) & 1u) && (64 * t + l < KTOP);
        unsigned long long m = __ballot(kb);
        int my = rank + __popcll(m & ((1ULL << l) - 1ULL));
        if (kb && my < POSTN) order[my] = 64 * t + l;
        rank += __popcll(m);
    }
    int kcnt = rank < POSTN ? rank : POSTN;
    __syncthreads();   // single wave: cheap; makes order[] visible
    for (int e = l; e < POSTN * 11; e += 64) {
        int r = e / 11, c = e - r * 11;
        float v = 0.0f;
        if (r < kcnt) {
            int i = order[r];
            int b = n * KTOP + i;
            if (c < 8)       v = cor[b * 8 + c];
            else if (c == 8) v = sc[b];
            else if (c == 9) v = (float)lab[b];
            else             v = 1.0f;
        }
        out[(n * POSTN + r) * 11 + c] = v;
    }
}

extern "C" void kernel_launch(void* const* d_in, const int* in_sizes, int n_in,
                              void* d_out, int out_size, void* d_ws, size_t ws_size,
                              hipStream_t stream) {
    const float* box_cls = (const float*)d_in[0];
    const float* box_reg = (const float*)d_in[1];
    const float* ctr     = (const float*)d_in[2];
    const float* ang     = (const float*)d_in[3];
    const float* anchors = (const float*)d_in[4];
    float* out = (float*)d_out;
    char* ws = (char*)d_ws;

    int* hist = (int*)(ws + HIST_OFF);
    int* cnt  = (int*)(ws + CNT_OFF);
    int* tbin = (int*)(ws + TBIN_OFF);
    int* pcnt = (int*)(ws + PCNT_OFF);
    unsigned long long* supT = (unsigned long long*)(ws + SUPT_OFF);
    unsigned long long* cand = (unsigned long long*)(ws + CAND_OFF);
    unsigned long long* skey = (unsigned long long*)(ws + SKEY_OFF);
    float* cor  = (float*)(ws + COR_OFF);
    float* area = (float*)(ws + AREA_OFF);
    int* lab    = (int*)(ws + LAB_OFF);
    float* sc   = (float*)(ws + SC_OFF);
    int* val    = (int*)(ws + VAL_OFF);
    float* ccx  = (float*)(ws + CCX_OFF);
    float* ccy  = (float*)(ws + CCY_OFF);
    float* crad = (float*)(ws + CRAD_OFF);
    int* pairs  = (int*)(ws + PAIRS_OFF);

    hipMemsetAsync(d_ws, 0, ZERO_BYTES, stream);
    k_hist     <<<dim3(HW / 256, NIMG), 256, 0, stream>>>(box_cls, ctr, hist);
    k_thresh   <<<NIMG, 256, 0, stream>>>(hist, tbin);
    k_collect  <<<dim3(HW / 256, NIMG), 256, 0, stream>>>(box_cls, ctr, tbin, cnt, cand);
    k_select   <<<NIMG, 256, 0, stream>>>(cand, cnt, skey);
    k_decode   <<<dim3(KTOP, NIMG), 64, 0, stream>>>(skey, box_reg, ang, anchors,
                                                     cor, area, lab, sc, val, ccx, ccy, crad);
    k_prefilter<<<dim3((KTOP * KTOP + 255) / 256, NIMG), 256, 0, stream>>>(
                   lab, ccx, ccy, crad, pcnt, pairs);
    k_iou      <<<dim3(PAIRCAP / 256, NIMG), 256, 0, stream>>>(pcnt, pairs, cor, area, supT);
    k_nms_out  <<<NIMG, 64, 0, stream>>>(supT, val, cor, sc, lab, out);
}